// Round 19
// baseline (52.423 us; speedup 1.0000x reference)
//
#include <hip/hip_runtime.h>
#include <hip/hip_bf16.h>
#include <math.h>

#define BB 16
#define CC 64
#define HW 4096
#define MM 1024
#define CK 8
#define CV 32
#define LOG2E 1.4426950408889634f

typedef float f32x4 __attribute__((ext_vector_type(4)));
typedef short s16x8 __attribute__((ext_vector_type(8)));

union U4 { uint4 u; s16x8 s; };

__device__ inline unsigned short bfu(float a) {           // RNE (prep only)
    __hip_bfloat16 h = __float2bfloat16(a);
    union { __hip_bfloat16 h; unsigned short u; } c; c.h = h; return c.u;
}
__device__ inline unsigned int pk2bf(float a, float b) {  // RNE pack
    return (unsigned int)bfu(a) | ((unsigned int)bfu(b) << 16);
}
__device__ inline unsigned int pk2bf_t(float a, float b) { // trunc pack (attn)
    return (__float_as_uint(a) >> 16) | (__float_as_uint(b) & 0xffff0000u);
}

// Pure-VALU bit-twiddle exp2: 10 single-issue VALU ops. A/B-verified FASTEST
// exp path on this kernel (R17 vs R18): fexp2i attn ~30us, v_exp_f32 attn
// ~40us (trans pipe is quarter-rate + hazard pad), OCML __builtin_exp2f ~43us.
// Scores bounded (|s|<~20) so (127+i)<<23 scale construction is safe.
__device__ inline float fexp2i(float s) {
    float r = rintf(s);                       // v_rndne_f32
    float f = s - r;                          // f in [-0.5, 0.5]
    float p = fmaf(f, 0.00961813f, 0.05550411f);
    p = fmaf(f, p, 0.24022651f);
    p = fmaf(f, p, 0.69314718f);
    p = fmaf(f, p, 1.0f);                     // 2^f, rel err ~4e-5
    float sc = __int_as_float(((int)r + 127) << 23);  // exact 2^r
    return p * sc;
}

// Workspace layout (bytes):
//   fxB  bf16 [b][q][8]            @ 0        (1,048,576)
//   gxA  bf16 [b][k][8]            @ 1048576  (262,144)
//   hxC  bf16 [b][ch][k]           @ 1310720  (1,048,576)
//   wvB  bf16 tiled [4][64][8]     @ 2359296  (4,096)
//   frag bf16 [b][g][4][64][8]     @ 2363392  (2,097,152)
#define FXB_OFF 0
#define GXA_OFF 1048576
#define HXC_OFF 1310720
#define WVB_OFF 2359296
#define FRG_OFF 2363392

// ---------------------------------------------------------------------------
// Kernel A: conv f/g/h split by OUTPUT channels (blockIdx.y = chunk:
// 0=f, 1=g, 2..5=h quarters). Pool via shfl_xor(1,2). hxC staged via LDS.
// ---------------------------------------------------------------------------
__global__ __launch_bounds__(256, 6) void prep_kernel(
    const float* __restrict__ x,
    const float* __restrict__ wf, const float* __restrict__ bf,
    const float* __restrict__ wg, const float* __restrict__ bg,
    const float* __restrict__ wh, const float* __restrict__ bh,
    const float* __restrict__ wv,
    unsigned short* __restrict__ fxB, unsigned short* __restrict__ gxA,
    unsigned short* __restrict__ hxC, unsigned short* __restrict__ wvB)
{
    __shared__ __align__(16) float wsm[8 * CC];
    __shared__ __align__(16) unsigned short sHp[64][8];

    int tid   = threadIdx.x;
    int chunk = blockIdx.y;            // 0=f 1=g 2..5=h
    const float* wsrc = (chunk == 0) ? wf : (chunk == 1) ? wg : (wh + (size_t)(chunk - 2) * 8 * CC);
    const float* bsrc = (chunk == 0) ? bf : (chunk == 1) ? bg : (bh + (chunk - 2) * 8);

    for (int i = tid; i < 8 * CC; i += 256) wsm[i] = wsrc[i];

    if (blockIdx.x == 0 && chunk == 0) {
        int t = tid >> 6, ll = tid & 63;
        const float* wr = wv + (size_t)(t * 16 + (ll & 15)) * CV + ((ll >> 4) * 8);
        uint4 wu;
        wu.x = pk2bf(wr[0], wr[1]); wu.y = pk2bf(wr[2], wr[3]);
        wu.z = pk2bf(wr[4], wr[5]); wu.w = pk2bf(wr[6], wr[7]);
        *(uint4*)(wvB + (size_t)tid * 8) = wu;
    }
    __syncthreads();

    int wave = tid >> 6, l = tid & 63;
    int wp = blockIdx.x * 4 + wave;
    int b  = wp >> 6;
    int t2 = wp & 63;
    int rpair = t2 >> 1, chalf = t2 & 1;
    int col = chalf * 32 + (l >> 2) * 2 + (l & 1);
    int row = rpair * 2 + ((l >> 1) & 1);
    int pix = row * 64 + col;

    float o8[8];
#pragma unroll
    for (int o = 0; o < 8; ++o) o8[o] = bsrc[o];

    const float* xp = x + (size_t)b * CC * HW + pix;
#pragma unroll 4
    for (int c4 = 0; c4 < CC; c4 += 4) {
        float v0 = xp[(c4 + 0) * HW];
        float v1 = xp[(c4 + 1) * HW];
        float v2 = xp[(c4 + 2) * HW];
        float v3 = xp[(c4 + 3) * HW];
#pragma unroll
        for (int o = 0; o < 8; ++o) {
            float4 w = *(const float4*)&wsm[o * CC + c4];
            o8[o] = fmaf(w.x, v0, fmaf(w.y, v1, fmaf(w.z, v2, fmaf(w.w, v3, o8[o]))));
        }
    }

    if (chunk == 0) {
        uint4 fu;
        fu.x = pk2bf(o8[0] * LOG2E, o8[1] * LOG2E);
        fu.y = pk2bf(o8[2] * LOG2E, o8[3] * LOG2E);
        fu.z = pk2bf(o8[4] * LOG2E, o8[5] * LOG2E);
        fu.w = pk2bf(o8[6] * LOG2E, o8[7] * LOG2E);
        *(uint4*)(fxB + (size_t)(b * HW + pix) * CK) = fu;
    } else {
#pragma unroll
        for (int o = 0; o < 8; ++o) {
            o8[o] = fmaxf(o8[o], __shfl_xor(o8[o], 1, 64));
            o8[o] = fmaxf(o8[o], __shfl_xor(o8[o], 2, 64));
        }
        int ppl = l >> 2;
        if (chunk == 1) {
            if ((l & 3) == 0) {
                uint4 gu;
                gu.x = pk2bf(o8[0], o8[1]); gu.y = pk2bf(o8[2], o8[3]);
                gu.z = pk2bf(o8[4], o8[5]); gu.w = pk2bf(o8[6], o8[7]);
                *(uint4*)(gxA + (size_t)(b * MM + t2 * 16 + ppl) * CK) = gu;
            }
        } else {
            if ((l & 3) == 0) {
                uint4 hu;
                hu.x = pk2bf(o8[0], o8[1]); hu.y = pk2bf(o8[2], o8[3]);
                hu.z = pk2bf(o8[4], o8[5]); hu.w = pk2bf(o8[6], o8[7]);
                *(uint4*)&sHp[wave * 16 + ppl][0] = hu;
            }
            __syncthreads();
            int ch = tid >> 5, j = tid & 31;
            unsigned int v = (unsigned int)sHp[2 * j][ch]
                           | ((unsigned int)sHp[2 * j + 1][ch] << 16);
            int ppb = (blockIdx.x * 4 & 63) * 16;
            int chg = (chunk - 2) * 8 + ch;
            *(unsigned int*)(hxC + (size_t)(b * CV + chg) * MM + ppb + 2 * j) = v;
        }
    }
}

// ---------------------------------------------------------------------------
// Kernel T: wave-exact operand tiles frag[b][g][4][64][8] (see R10).
// ---------------------------------------------------------------------------
__global__ __launch_bounds__(256) void tile_kernel(
    const unsigned short* __restrict__ gxA, const unsigned short* __restrict__ hxC,
    unsigned short* __restrict__ frag)
{
    int bg = blockIdx.x;
    int b  = bg >> 5, g = bg & 31;
    int tid = threadIdx.x;
    int which = tid >> 6, l = tid & 63;
    int q16 = l & 15, h = l >> 4;
    int prm = ((q16 & 12) << 1) | (q16 & 3);

    const unsigned short* src;
    if (which < 2) {
        src = gxA + (size_t)(b * MM + g * 32 + prm + (which ? 4 : 0)) * CK;
    } else {
        src = hxC + (size_t)(b * CV + prm + ((which == 3) ? 4 : 0)) * MM + g * 32 + h * 8;
    }
    uint4 v = *(const uint4*)src;
    *(uint4*)(frag + ((size_t)bg * 4 + which) * 64 * 8 + (size_t)l * 8) = v;
}

// ---------------------------------------------------------------------------
// Kernel B: MFMA flash attention. Block = 32 queries, 512 thr (8 waves).
// Wave w: Q-tile qh=w&1, key-quarter kq=w>>1 (256 keys, 8 frag groups).
// R19: R17's exact attn body (fexp2i -- the A/B-proven fastest exp) with
// __launch_bounds__(512,8). R17's probe measured this body at 36 VGPR, so
// it fits the 64-VGPR cap of (512,8) WITHOUT spill (R8/R12 spills were
// bigger bodies: 2-Q-tile / prefetch-dbuf). Probe also showed
// VALUBusy+MfmaUtil == Occupancy == 58% -> issue-bound at the 4-wave cap;
// 8 resident waves/SIMD fill the idle 42% of issue slots.
// ---------------------------------------------------------------------------
__global__ __launch_bounds__(512, 8) void attn_kernel(
    const float* __restrict__ x,
    const unsigned short* __restrict__ fxB, const unsigned short* __restrict__ frag,
    const unsigned short* __restrict__ wvB,
    const float* __restrict__ bv, const float* __restrict__ gamma,
    float* __restrict__ out)
{
    __shared__ float sAcc[2][4][8][64];
    __shared__ float sSum[2][4][64];

    int tid = threadIdx.x;
    int l   = tid & 63;
    int w   = tid >> 6;
    int qh  = w & 1;
    int kq  = w >> 1;
    int b   = blockIdx.x >> 7;
    int qb  = (blockIdx.x & 127) * 32;
    int q16 = l & 15;
    int h   = l >> 4;
    bool lo16 = (l < 16);

    U4 qf;
    {
        uint4 v = *(const uint4*)(fxB + (size_t)(b * HW + qb + qh * 16 + q16) * CK);
        if (!lo16) { v.x = 0; v.y = 0; v.z = 0; v.w = 0; }
        qf.u = v;
    }

    f32x4 zz = {0.f, 0.f, 0.f, 0.f};
    f32x4 acc0 = zz, acc1 = zz;
    float ssum = 0.f;

    const unsigned short* fb = frag + ((size_t)(b * 32 + kq * 8) * 4) * 64 * 8
                                    + (size_t)l * 8;

#pragma unroll 2
    for (int gi = 0; gi < 8; ++gi) {
        U4 ga, gb2, v0, v1;
        ga.u  = *(const uint4*)(fb + 0 * 512);
        gb2.u = *(const uint4*)(fb + 1 * 512);
        v0.u  = *(const uint4*)(fb + 2 * 512);
        v1.u  = *(const uint4*)(fb + 3 * 512);
        fb += 2048;

        f32x4 s0 = __builtin_amdgcn_mfma_f32_16x16x32_bf16(ga.s,  qf.s, zz, 0, 0, 0);
        f32x4 s1 = __builtin_amdgcn_mfma_f32_16x16x32_bf16(gb2.s, qf.s, zz, 0, 0, 0);
        float e0 = fexp2i(s0.x), e1 = fexp2i(s0.y), e2 = fexp2i(s0.z), e3 = fexp2i(s0.w);
        float e4 = fexp2i(s1.x), e5 = fexp2i(s1.y), e6 = fexp2i(s1.z), e7 = fexp2i(s1.w);
        ssum += ((e0 + e1) + (e2 + e3)) + ((e4 + e5) + (e6 + e7));
        U4 bp;
        bp.u.x = pk2bf_t(e0, e1); bp.u.y = pk2bf_t(e2, e3);
        bp.u.z = pk2bf_t(e4, e5); bp.u.w = pk2bf_t(e6, e7);
        acc0 = __builtin_amdgcn_mfma_f32_16x16x32_bf16(v0.s, bp.s, acc0, 0, 0, 0);
        acc1 = __builtin_amdgcn_mfma_f32_16x16x32_bf16(v1.s, bp.s, acc1, 0, 0, 0);
    }

#pragma unroll
    for (int e = 0; e < 4; ++e) {
        sAcc[qh][kq][e][l]     = acc0[e];
        sAcc[qh][kq][4 + e][l] = acc1[e];
    }
    sSum[qh][kq][l] = ssum;
    __syncthreads();

    int qt_f = w & 1;
    int ot   = w >> 1;
    f32x4 ca0 = zz, ca1 = zz;
    float cs = 0.f;
#pragma unroll
    for (int k2 = 0; k2 < 4; ++k2) {
#pragma unroll
        for (int e = 0; e < 4; ++e) {
            ca0[e] += sAcc[qt_f][k2][e][l];
            ca1[e] += sAcc[qt_f][k2][4 + e][l];
        }
        cs += sSum[qt_f][k2][l];
    }
    cs += __shfl_xor(cs, 16, 64);
    cs += __shfl_xor(cs, 32, 64);
    float inv = 1.0f / cs;

    U4 mb;
    mb.u.x = pk2bf_t(ca0.x * inv, ca0.y * inv);
    mb.u.y = pk2bf_t(ca0.z * inv, ca0.w * inv);
    mb.u.z = pk2bf_t(ca1.x * inv, ca1.y * inv);
    mb.u.w = pk2bf_t(ca1.z * inv, ca1.w * inv);

    float gm = gamma[0];
    int q = qb + qt_f * 16 + q16;
    const float* xq = x + (size_t)b * CC * HW + q;
    float*       oq = out + (size_t)b * CC * HW + q;
    U4 wva;
    wva.u = *(const uint4*)(wvB + (size_t)(ot * 64 + l) * CK);
    f32x4 d = __builtin_amdgcn_mfma_f32_16x16x32_bf16(wva.s, mb.s, zz, 0, 0, 0);
#pragma unroll
    for (int r = 0; r < 4; ++r) {
        int o = ot * 16 + h * 4 + r;
        oq[(size_t)o * HW] = xq[(size_t)o * HW] + gm * (d[r] + bv[o]);
    }
}

extern "C" void kernel_launch(void* const* d_in, const int* in_sizes, int n_in,
                              void* d_out, int out_size, void* d_ws, size_t ws_size,
                              hipStream_t stream) {
    const float* x     = (const float*)d_in[0];
    const float* wf    = (const float*)d_in[1];
    const float* bf    = (const float*)d_in[2];
    const float* wg    = (const float*)d_in[3];
    const float* bg    = (const float*)d_in[4];
    const float* wh    = (const float*)d_in[5];
    const float* bh    = (const float*)d_in[6];
    const float* wv    = (const float*)d_in[7];
    const float* bv    = (const float*)d_in[8];
    const float* gamma = (const float*)d_in[9];
    float* out = (float*)d_out;
    char* ws = (char*)d_ws;

    unsigned short* fxB  = (unsigned short*)(ws + FXB_OFF);
    unsigned short* gxA  = (unsigned short*)(ws + GXA_OFF);
    unsigned short* hxC  = (unsigned short*)(ws + HXC_OFF);
    unsigned short* wvB  = (unsigned short*)(ws + WVB_OFF);
    unsigned short* frag = (unsigned short*)(ws + FRG_OFF);

    prep_kernel<<<dim3(256, 6), 256, 0, stream>>>(x, wf, bf, wg, bg, wh, bh, wv,
                                                  fxB, gxA, hxC, wvB);
    tile_kernel<<<512, 256, 0, stream>>>(gxA, hxC, frag);
    attn_kernel<<<2048, 512, 0, stream>>>(x, fxB, frag, wvB, bv, gamma, out);
}

// Round 20
// 52.388 us; speedup vs baseline: 1.0007x; 1.0007x over previous
//
#include <hip/hip_runtime.h>
#include <hip/hip_bf16.h>
#include <math.h>

#define BB 16
#define CC 64
#define HW 4096
#define MM 1024
#define CK 8
#define CV 32
#define LOG2E 1.4426950408889634f

typedef float f32x4 __attribute__((ext_vector_type(4)));
typedef short s16x8 __attribute__((ext_vector_type(8)));

union U4 { uint4 u; s16x8 s; };

__device__ inline unsigned short bfu(float a) {           // RNE (prep only)
    __hip_bfloat16 h = __float2bfloat16(a);
    union { __hip_bfloat16 h; unsigned short u; } c; c.h = h; return c.u;
}
__device__ inline unsigned int pk2bf(float a, float b) {  // RNE pack
    return (unsigned int)bfu(a) | ((unsigned int)bfu(b) << 16);
}
__device__ inline unsigned int pk2bf_t(float a, float b) { // trunc pack (attn)
    return (__float_as_uint(a) >> 16) | (__float_as_uint(b) & 0xffff0000u);
}

// Pure-VALU bit-twiddle exp2: ~9 single-issue VALU ops. A/B-verified FASTEST
// exp path on this kernel: fexp2i attn ~30us (R17 ledger) vs v_exp_f32 ~40us
// (R18: trans pipe quarter-rate + hazard pad) vs OCML __builtin_exp2f ~40+us
// (R2-R11). Scores bounded (|s|<~20) so (127+i)<<23 construction is safe.
__device__ inline float fexp2i(float s) {
    float r = rintf(s);                       // v_rndne_f32
    float f = s - r;                          // f in [-0.5, 0.5]
    float p = fmaf(f, 0.00961813f, 0.05550411f);
    p = fmaf(f, p, 0.24022651f);
    p = fmaf(f, p, 0.69314718f);
    p = fmaf(f, p, 1.0f);                     // 2^f, rel err ~4e-5
    float sc = __int_as_float(((int)r + 127) << 23);  // exact 2^r
    return p * sc;
}

// Workspace layout (bytes):
//   fxB  bf16 [b][q][8]            @ 0        (1,048,576)
//   gxA  bf16 [b][k][8]            @ 1048576  (262,144)
//   hxC  bf16 [b][ch][k]           @ 1310720  (1,048,576)
//   wvB  bf16 tiled [4][64][8]     @ 2359296  (4,096)
//   frag bf16 [b][g][4][64][8]     @ 2363392  (2,097,152)
#define FXB_OFF 0
#define GXA_OFF 1048576
#define HXC_OFF 1310720
#define WVB_OFF 2359296
#define FRG_OFF 2363392

// ---------------------------------------------------------------------------
// Kernel A: conv f/g/h split by OUTPUT channels (blockIdx.y = chunk:
// 0=f, 1=g, 2..5=h quarters). Pool via shfl_xor(1,2). hxC staged via LDS.
// ---------------------------------------------------------------------------
__global__ __launch_bounds__(256, 6) void prep_kernel(
    const float* __restrict__ x,
    const float* __restrict__ wf, const float* __restrict__ bf,
    const float* __restrict__ wg, const float* __restrict__ bg,
    const float* __restrict__ wh, const float* __restrict__ bh,
    const float* __restrict__ wv,
    unsigned short* __restrict__ fxB, unsigned short* __restrict__ gxA,
    unsigned short* __restrict__ hxC, unsigned short* __restrict__ wvB)
{
    __shared__ __align__(16) float wsm[8 * CC];
    __shared__ __align__(16) unsigned short sHp[64][8];

    int tid   = threadIdx.x;
    int chunk = blockIdx.y;            // 0=f 1=g 2..5=h
    const float* wsrc = (chunk == 0) ? wf : (chunk == 1) ? wg : (wh + (size_t)(chunk - 2) * 8 * CC);
    const float* bsrc = (chunk == 0) ? bf : (chunk == 1) ? bg : (bh + (chunk - 2) * 8);

    for (int i = tid; i < 8 * CC; i += 256) wsm[i] = wsrc[i];

    if (blockIdx.x == 0 && chunk == 0) {
        int t = tid >> 6, ll = tid & 63;
        const float* wr = wv + (size_t)(t * 16 + (ll & 15)) * CV + ((ll >> 4) * 8);
        uint4 wu;
        wu.x = pk2bf(wr[0], wr[1]); wu.y = pk2bf(wr[2], wr[3]);
        wu.z = pk2bf(wr[4], wr[5]); wu.w = pk2bf(wr[6], wr[7]);
        *(uint4*)(wvB + (size_t)tid * 8) = wu;
    }
    __syncthreads();

    int wave = tid >> 6, l = tid & 63;
    int wp = blockIdx.x * 4 + wave;
    int b  = wp >> 6;
    int t2 = wp & 63;
    int rpair = t2 >> 1, chalf = t2 & 1;
    int col = chalf * 32 + (l >> 2) * 2 + (l & 1);
    int row = rpair * 2 + ((l >> 1) & 1);
    int pix = row * 64 + col;

    float o8[8];
#pragma unroll
    for (int o = 0; o < 8; ++o) o8[o] = bsrc[o];

    const float* xp = x + (size_t)b * CC * HW + pix;
#pragma unroll 4
    for (int c4 = 0; c4 < CC; c4 += 4) {
        float v0 = xp[(c4 + 0) * HW];
        float v1 = xp[(c4 + 1) * HW];
        float v2 = xp[(c4 + 2) * HW];
        float v3 = xp[(c4 + 3) * HW];
#pragma unroll
        for (int o = 0; o < 8; ++o) {
            float4 w = *(const float4*)&wsm[o * CC + c4];
            o8[o] = fmaf(w.x, v0, fmaf(w.y, v1, fmaf(w.z, v2, fmaf(w.w, v3, o8[o]))));
        }
    }

    if (chunk == 0) {
        uint4 fu;
        fu.x = pk2bf(o8[0] * LOG2E, o8[1] * LOG2E);
        fu.y = pk2bf(o8[2] * LOG2E, o8[3] * LOG2E);
        fu.z = pk2bf(o8[4] * LOG2E, o8[5] * LOG2E);
        fu.w = pk2bf(o8[6] * LOG2E, o8[7] * LOG2E);
        *(uint4*)(fxB + (size_t)(b * HW + pix) * CK) = fu;
    } else {
#pragma unroll
        for (int o = 0; o < 8; ++o) {
            o8[o] = fmaxf(o8[o], __shfl_xor(o8[o], 1, 64));
            o8[o] = fmaxf(o8[o], __shfl_xor(o8[o], 2, 64));
        }
        int ppl = l >> 2;
        if (chunk == 1) {
            if ((l & 3) == 0) {
                uint4 gu;
                gu.x = pk2bf(o8[0], o8[1]); gu.y = pk2bf(o8[2], o8[3]);
                gu.z = pk2bf(o8[4], o8[5]); gu.w = pk2bf(o8[6], o8[7]);
                *(uint4*)(gxA + (size_t)(b * MM + t2 * 16 + ppl) * CK) = gu;
            }
        } else {
            if ((l & 3) == 0) {
                uint4 hu;
                hu.x = pk2bf(o8[0], o8[1]); hu.y = pk2bf(o8[2], o8[3]);
                hu.z = pk2bf(o8[4], o8[5]); hu.w = pk2bf(o8[6], o8[7]);
                *(uint4*)&sHp[wave * 16 + ppl][0] = hu;
            }
            __syncthreads();
            int ch = tid >> 5, j = tid & 31;
            unsigned int v = (unsigned int)sHp[2 * j][ch]
                           | ((unsigned int)sHp[2 * j + 1][ch] << 16);
            int ppb = (blockIdx.x * 4 & 63) * 16;
            int chg = (chunk - 2) * 8 + ch;
            *(unsigned int*)(hxC + (size_t)(b * CV + chg) * MM + ppb + 2 * j) = v;
        }
    }
}

// ---------------------------------------------------------------------------
// Kernel T: wave-exact operand tiles frag[b][g][4][64][8] (see R10).
// ---------------------------------------------------------------------------
__global__ __launch_bounds__(256) void tile_kernel(
    const unsigned short* __restrict__ gxA, const unsigned short* __restrict__ hxC,
    unsigned short* __restrict__ frag)
{
    int bg = blockIdx.x;
    int b  = bg >> 5, g = bg & 31;
    int tid = threadIdx.x;
    int which = tid >> 6, l = tid & 63;
    int q16 = l & 15, h = l >> 4;
    int prm = ((q16 & 12) << 1) | (q16 & 3);

    const unsigned short* src;
    if (which < 2) {
        src = gxA + (size_t)(b * MM + g * 32 + prm + (which ? 4 : 0)) * CK;
    } else {
        src = hxC + (size_t)(b * CV + prm + ((which == 3) ? 4 : 0)) * MM + g * 32 + h * 8;
    }
    uint4 v = *(const uint4*)src;
    *(uint4*)(frag + ((size_t)bg * 4 + which) * 64 * 8 + (size_t)l * 8) = v;
}

// ---------------------------------------------------------------------------
// Kernel B: MFMA flash attention. Block = 32 queries, 512 thr (8 waves).
// Wave w: Q-tile qh=w&1, key-quarter kq=w>>1 (256 keys, 8 frag groups).
// R20 = R17's attn EXACTLY (fexp2i, single chain) minus the diagnostic
// probe. __launch_bounds__(512,4): the ONLY proven-safe bound -- (512,8)
// regressed 30->46us in R19 (64-VGPR cap degrades codegen; residency was
// already 8 waves/SIMD at 36-40 VGPR, so the tighter cap bought nothing).
// ---------------------------------------------------------------------------
__global__ __launch_bounds__(512, 4) void attn_kernel(
    const float* __restrict__ x,
    const unsigned short* __restrict__ fxB, const unsigned short* __restrict__ frag,
    const unsigned short* __restrict__ wvB,
    const float* __restrict__ bv, const float* __restrict__ gamma,
    float* __restrict__ out)
{
    __shared__ float sAcc[2][4][8][64];
    __shared__ float sSum[2][4][64];

    int tid = threadIdx.x;
    int l   = tid & 63;
    int w   = tid >> 6;
    int qh  = w & 1;
    int kq  = w >> 1;
    int b   = blockIdx.x >> 7;
    int qb  = (blockIdx.x & 127) * 32;
    int q16 = l & 15;
    int h   = l >> 4;
    bool lo16 = (l < 16);

    U4 qf;
    {
        uint4 v = *(const uint4*)(fxB + (size_t)(b * HW + qb + qh * 16 + q16) * CK);
        if (!lo16) { v.x = 0; v.y = 0; v.z = 0; v.w = 0; }
        qf.u = v;
    }

    f32x4 zz = {0.f, 0.f, 0.f, 0.f};
    f32x4 acc0 = zz, acc1 = zz;
    float ssum = 0.f;

    const unsigned short* fb = frag + ((size_t)(b * 32 + kq * 8) * 4) * 64 * 8
                                    + (size_t)l * 8;

#pragma unroll 2
    for (int gi = 0; gi < 8; ++gi) {
        U4 ga, gb2, v0, v1;
        ga.u  = *(const uint4*)(fb + 0 * 512);
        gb2.u = *(const uint4*)(fb + 1 * 512);
        v0.u  = *(const uint4*)(fb + 2 * 512);
        v1.u  = *(const uint4*)(fb + 3 * 512);
        fb += 2048;

        f32x4 s0 = __builtin_amdgcn_mfma_f32_16x16x32_bf16(ga.s,  qf.s, zz, 0, 0, 0);
        f32x4 s1 = __builtin_amdgcn_mfma_f32_16x16x32_bf16(gb2.s, qf.s, zz, 0, 0, 0);
        float e0 = fexp2i(s0.x), e1 = fexp2i(s0.y), e2 = fexp2i(s0.z), e3 = fexp2i(s0.w);
        float e4 = fexp2i(s1.x), e5 = fexp2i(s1.y), e6 = fexp2i(s1.z), e7 = fexp2i(s1.w);
        ssum += ((e0 + e1) + (e2 + e3)) + ((e4 + e5) + (e6 + e7));
        U4 bp;
        bp.u.x = pk2bf_t(e0, e1); bp.u.y = pk2bf_t(e2, e3);
        bp.u.z = pk2bf_t(e4, e5); bp.u.w = pk2bf_t(e6, e7);
        acc0 = __builtin_amdgcn_mfma_f32_16x16x32_bf16(v0.s, bp.s, acc0, 0, 0, 0);
        acc1 = __builtin_amdgcn_mfma_f32_16x16x32_bf16(v1.s, bp.s, acc1, 0, 0, 0);
    }

#pragma unroll
    for (int e = 0; e < 4; ++e) {
        sAcc[qh][kq][e][l]     = acc0[e];
        sAcc[qh][kq][4 + e][l] = acc1[e];
    }
    sSum[qh][kq][l] = ssum;
    __syncthreads();

    int qt_f = w & 1;
    int ot   = w >> 1;
    f32x4 ca0 = zz, ca1 = zz;
    float cs = 0.f;
#pragma unroll
    for (int k2 = 0; k2 < 4; ++k2) {
#pragma unroll
        for (int e = 0; e < 4; ++e) {
            ca0[e] += sAcc[qt_f][k2][e][l];
            ca1[e] += sAcc[qt_f][k2][4 + e][l];
        }
        cs += sSum[qt_f][k2][l];
    }
    cs += __shfl_xor(cs, 16, 64);
    cs += __shfl_xor(cs, 32, 64);
    float inv = 1.0f / cs;

    U4 mb;
    mb.u.x = pk2bf_t(ca0.x * inv, ca0.y * inv);
    mb.u.y = pk2bf_t(ca0.z * inv, ca0.w * inv);
    mb.u.z = pk2bf_t(ca1.x * inv, ca1.y * inv);
    mb.u.w = pk2bf_t(ca1.z * inv, ca1.w * inv);

    float gm = gamma[0];
    int q = qb + qt_f * 16 + q16;
    const float* xq = x + (size_t)b * CC * HW + q;
    float*       oq = out + (size_t)b * CC * HW + q;
    U4 wva;
    wva.u = *(const uint4*)(wvB + (size_t)(ot * 64 + l) * CK);
    f32x4 d = __builtin_amdgcn_mfma_f32_16x16x32_bf16(wva.s, mb.s, zz, 0, 0, 0);
#pragma unroll
    for (int r = 0; r < 4; ++r) {
        int o = ot * 16 + h * 4 + r;
        oq[(size_t)o * HW] = xq[(size_t)o * HW] + gm * (d[r] + bv[o]);
    }
}

extern "C" void kernel_launch(void* const* d_in, const int* in_sizes, int n_in,
                              void* d_out, int out_size, void* d_ws, size_t ws_size,
                              hipStream_t stream) {
    const float* x     = (const float*)d_in[0];
    const float* wf    = (const float*)d_in[1];
    const float* bf    = (const float*)d_in[2];
    const float* wg    = (const float*)d_in[3];
    const float* bg    = (const float*)d_in[4];
    const float* wh    = (const float*)d_in[5];
    const float* bh    = (const float*)d_in[6];
    const float* wv    = (const float*)d_in[7];
    const float* bv    = (const float*)d_in[8];
    const float* gamma = (const float*)d_in[9];
    float* out = (float*)d_out;
    char* ws = (char*)d_ws;

    unsigned short* fxB  = (unsigned short*)(ws + FXB_OFF);
    unsigned short* gxA  = (unsigned short*)(ws + GXA_OFF);
    unsigned short* hxC  = (unsigned short*)(ws + HXC_OFF);
    unsigned short* wvB  = (unsigned short*)(ws + WVB_OFF);
    unsigned short* frag = (unsigned short*)(ws + FRG_OFF);

    prep_kernel<<<dim3(256, 6), 256, 0, stream>>>(x, wf, bf, wg, bg, wh, bh, wv,
                                                  fxB, gxA, hxC, wvB);
    tile_kernel<<<512, 256, 0, stream>>>(gxA, hxC, frag);
    attn_kernel<<<2048, 512, 0, stream>>>(x, fxB, frag, wvB, bv, gamma, out);
}

// Round 21
// 46.973 us; speedup vs baseline: 1.1160x; 1.1153x over previous
//
#include <hip/hip_runtime.h>
#include <hip/hip_bf16.h>
#include <math.h>

#define BB 16
#define CC 64
#define HW 4096
#define MM 1024
#define CK 8
#define CV 32
#define LOG2E 1.4426950408889634f

typedef float f32x4 __attribute__((ext_vector_type(4)));
typedef short s16x8 __attribute__((ext_vector_type(8)));

union U4 { uint4 u; s16x8 s; };

__device__ inline unsigned short bfu(float a) {           // RNE (prep only)
    __hip_bfloat16 h = __float2bfloat16(a);
    union { __hip_bfloat16 h; unsigned short u; } c; c.h = h; return c.u;
}
__device__ inline unsigned int pk2bf(float a, float b) {  // RNE pack
    return (unsigned int)bfu(a) | ((unsigned int)bfu(b) << 16);
}
__device__ inline unsigned int pk2bf_t(float a, float b) { // trunc pack (attn)
    return (__float_as_uint(a) >> 16) | (__float_as_uint(b) & 0xffff0000u);
}

// Hardware exp2 (v_exp_f32, trans pipe). DIRECT A/B (R18 vs R20, both
// probe-free, (512,4)): hwexp2 total 46.25us vs fexp2i 52.39us -- the trans
// pipe overlaps VALU pack/ssum; the 9-op VALU poly sits on the critical
// path. (Earlier "fexp2i ~30us" ledger entry was a probe-subtraction
// artifact; direct totals are authoritative.)
__device__ inline float hwexp2(float s) {
#if __has_builtin(__builtin_amdgcn_exp2f)
    return __builtin_amdgcn_exp2f(s);
#else
    float r;
    asm volatile("v_exp_f32 %0, %1\n\ts_nop 1" : "=v"(r) : "v"(s));
    return r;
#endif
}

// Workspace layout (bytes):
//   fxB  bf16 [b][q][8]            @ 0        (1,048,576)
//   gxA  bf16 [b][k][8]            @ 1048576  (262,144)
//   hxC  bf16 [b][ch][k]           @ 1310720  (1,048,576)
//   wvB  bf16 tiled [4][64][8]     @ 2359296  (4,096)
//   frag bf16 [b][g][4][64][8]     @ 2363392  (2,097,152)
#define FXB_OFF 0
#define GXA_OFF 1048576
#define HXC_OFF 1310720
#define WVB_OFF 2359296
#define FRG_OFF 2363392

// ---------------------------------------------------------------------------
// Kernel A: conv f/g/h split by OUTPUT channels (blockIdx.y = chunk:
// 0=f, 1=g, 2..5=h quarters). Pool via shfl_xor(1,2). hxC staged via LDS.
// ---------------------------------------------------------------------------
__global__ __launch_bounds__(256, 6) void prep_kernel(
    const float* __restrict__ x,
    const float* __restrict__ wf, const float* __restrict__ bf,
    const float* __restrict__ wg, const float* __restrict__ bg,
    const float* __restrict__ wh, const float* __restrict__ bh,
    const float* __restrict__ wv,
    unsigned short* __restrict__ fxB, unsigned short* __restrict__ gxA,
    unsigned short* __restrict__ hxC, unsigned short* __restrict__ wvB)
{
    __shared__ __align__(16) float wsm[8 * CC];
    __shared__ __align__(16) unsigned short sHp[64][8];

    int tid   = threadIdx.x;
    int chunk = blockIdx.y;            // 0=f 1=g 2..5=h
    const float* wsrc = (chunk == 0) ? wf : (chunk == 1) ? wg : (wh + (size_t)(chunk - 2) * 8 * CC);
    const float* bsrc = (chunk == 0) ? bf : (chunk == 1) ? bg : (bh + (chunk - 2) * 8);

    for (int i = tid; i < 8 * CC; i += 256) wsm[i] = wsrc[i];

    if (blockIdx.x == 0 && chunk == 0) {
        int t = tid >> 6, ll = tid & 63;
        const float* wr = wv + (size_t)(t * 16 + (ll & 15)) * CV + ((ll >> 4) * 8);
        uint4 wu;
        wu.x = pk2bf(wr[0], wr[1]); wu.y = pk2bf(wr[2], wr[3]);
        wu.z = pk2bf(wr[4], wr[5]); wu.w = pk2bf(wr[6], wr[7]);
        *(uint4*)(wvB + (size_t)tid * 8) = wu;
    }
    __syncthreads();

    int wave = tid >> 6, l = tid & 63;
    int wp = blockIdx.x * 4 + wave;
    int b  = wp >> 6;
    int t2 = wp & 63;
    int rpair = t2 >> 1, chalf = t2 & 1;
    int col = chalf * 32 + (l >> 2) * 2 + (l & 1);
    int row = rpair * 2 + ((l >> 1) & 1);
    int pix = row * 64 + col;

    float o8[8];
#pragma unroll
    for (int o = 0; o < 8; ++o) o8[o] = bsrc[o];

    const float* xp = x + (size_t)b * CC * HW + pix;
#pragma unroll 4
    for (int c4 = 0; c4 < CC; c4 += 4) {
        float v0 = xp[(c4 + 0) * HW];
        float v1 = xp[(c4 + 1) * HW];
        float v2 = xp[(c4 + 2) * HW];
        float v3 = xp[(c4 + 3) * HW];
#pragma unroll
        for (int o = 0; o < 8; ++o) {
            float4 w = *(const float4*)&wsm[o * CC + c4];
            o8[o] = fmaf(w.x, v0, fmaf(w.y, v1, fmaf(w.z, v2, fmaf(w.w, v3, o8[o]))));
        }
    }

    if (chunk == 0) {
        uint4 fu;
        fu.x = pk2bf(o8[0] * LOG2E, o8[1] * LOG2E);
        fu.y = pk2bf(o8[2] * LOG2E, o8[3] * LOG2E);
        fu.z = pk2bf(o8[4] * LOG2E, o8[5] * LOG2E);
        fu.w = pk2bf(o8[6] * LOG2E, o8[7] * LOG2E);
        *(uint4*)(fxB + (size_t)(b * HW + pix) * CK) = fu;
    } else {
#pragma unroll
        for (int o = 0; o < 8; ++o) {
            o8[o] = fmaxf(o8[o], __shfl_xor(o8[o], 1, 64));
            o8[o] = fmaxf(o8[o], __shfl_xor(o8[o], 2, 64));
        }
        int ppl = l >> 2;
        if (chunk == 1) {
            if ((l & 3) == 0) {
                uint4 gu;
                gu.x = pk2bf(o8[0], o8[1]); gu.y = pk2bf(o8[2], o8[3]);
                gu.z = pk2bf(o8[4], o8[5]); gu.w = pk2bf(o8[6], o8[7]);
                *(uint4*)(gxA + (size_t)(b * MM + t2 * 16 + ppl) * CK) = gu;
            }
        } else {
            if ((l & 3) == 0) {
                uint4 hu;
                hu.x = pk2bf(o8[0], o8[1]); hu.y = pk2bf(o8[2], o8[3]);
                hu.z = pk2bf(o8[4], o8[5]); hu.w = pk2bf(o8[6], o8[7]);
                *(uint4*)&sHp[wave * 16 + ppl][0] = hu;
            }
            __syncthreads();
            int ch = tid >> 5, j = tid & 31;
            unsigned int v = (unsigned int)sHp[2 * j][ch]
                           | ((unsigned int)sHp[2 * j + 1][ch] << 16);
            int ppb = (blockIdx.x * 4 & 63) * 16;
            int chg = (chunk - 2) * 8 + ch;
            *(unsigned int*)(hxC + (size_t)(b * CV + chg) * MM + ppb + 2 * j) = v;
        }
    }
}

// ---------------------------------------------------------------------------
// Kernel T: wave-exact operand tiles frag[b][g][4][64][8] (see R10).
// ---------------------------------------------------------------------------
__global__ __launch_bounds__(256) void tile_kernel(
    const unsigned short* __restrict__ gxA, const unsigned short* __restrict__ hxC,
    unsigned short* __restrict__ frag)
{
    int bg = blockIdx.x;
    int b  = bg >> 5, g = bg & 31;
    int tid = threadIdx.x;
    int which = tid >> 6, l = tid & 63;
    int q16 = l & 15, h = l >> 4;
    int prm = ((q16 & 12) << 1) | (q16 & 3);

    const unsigned short* src;
    if (which < 2) {
        src = gxA + (size_t)(b * MM + g * 32 + prm + (which ? 4 : 0)) * CK;
    } else {
        src = hxC + (size_t)(b * CV + prm + ((which == 3) ? 4 : 0)) * MM + g * 32 + h * 8;
    }
    uint4 v = *(const uint4*)src;
    *(uint4*)(frag + ((size_t)bg * 4 + which) * 64 * 8 + (size_t)l * 8) = v;
}

// ---------------------------------------------------------------------------
// Kernel B: MFMA flash attention. Block = 32 queries, 512 thr (8 waves).
// Wave w: Q-tile qh=w&1, key-quarter kq=w>>1 (256 keys, 8 frag groups).
// R21 = R18 (hwexp2, the direct-A/B best at 46.25us total) + software
// pipelining: group gi+1's frag loads AND QK MFMAs issue BEFORE group gi's
// exp/pack/PV (next-QK is independent -> MFMA pipe fills while exp runs on
// the trans pipe and pack on VALU); PV accumulators split by group parity
// (accA/accB) halving the dependent-MFMA chain 8->4. Full unroll keeps all
// rotation static. ~80 VGPR < the (512,4) 128 cap; R19==R20 proved attn is
// NOT occupancy-limited, so (512,4) stays.
// ---------------------------------------------------------------------------
__global__ __launch_bounds__(512, 4) void attn_kernel(
    const float* __restrict__ x,
    const unsigned short* __restrict__ fxB, const unsigned short* __restrict__ frag,
    const unsigned short* __restrict__ wvB,
    const float* __restrict__ bv, const float* __restrict__ gamma,
    float* __restrict__ out)
{
    __shared__ float sAcc[2][4][8][64];
    __shared__ float sSum[2][4][64];

    int tid = threadIdx.x;
    int l   = tid & 63;
    int w   = tid >> 6;
    int qh  = w & 1;
    int kq  = w >> 1;
    int b   = blockIdx.x >> 7;
    int qb  = (blockIdx.x & 127) * 32;
    int q16 = l & 15;
    int h   = l >> 4;
    bool lo16 = (l < 16);

    U4 qf;
    {
        uint4 v = *(const uint4*)(fxB + (size_t)(b * HW + qb + qh * 16 + q16) * CK);
        if (!lo16) { v.x = 0; v.y = 0; v.z = 0; v.w = 0; }
        qf.u = v;
    }

    f32x4 zz = {0.f, 0.f, 0.f, 0.f};
    f32x4 accA0 = zz, accA1 = zz, accB0 = zz, accB1 = zz;
    float ssum = 0.f;

    const unsigned short* fb = frag + ((size_t)(b * 32 + kq * 8) * 4) * 64 * 8
                                    + (size_t)l * 8;

    // prologue: group 0 frags + its QK
    U4 v0, v1;
    f32x4 s0, s1;
    {
        U4 ga, gb2;
        ga.u  = *(const uint4*)(fb + 0 * 512);
        gb2.u = *(const uint4*)(fb + 1 * 512);
        v0.u  = *(const uint4*)(fb + 2 * 512);
        v1.u  = *(const uint4*)(fb + 3 * 512);
        s0 = __builtin_amdgcn_mfma_f32_16x16x32_bf16(ga.s,  qf.s, zz, 0, 0, 0);
        s1 = __builtin_amdgcn_mfma_f32_16x16x32_bf16(gb2.s, qf.s, zz, 0, 0, 0);
    }

#pragma unroll
    for (int gi = 0; gi < 8; ++gi) {
        // issue next group's loads + QK first (independent of current work)
        U4 v0n, v1n;
        f32x4 s0n, s1n;
        if (gi < 7) {
            const unsigned short* fn = fb + (size_t)(gi + 1) * 2048;
            U4 gan, gbn;
            gan.u = *(const uint4*)(fn + 0 * 512);
            gbn.u = *(const uint4*)(fn + 1 * 512);
            v0n.u = *(const uint4*)(fn + 2 * 512);
            v1n.u = *(const uint4*)(fn + 3 * 512);
            s0n = __builtin_amdgcn_mfma_f32_16x16x32_bf16(gan.s, qf.s, zz, 0, 0, 0);
            s1n = __builtin_amdgcn_mfma_f32_16x16x32_bf16(gbn.s, qf.s, zz, 0, 0, 0);
        }

        // current group's softmax + PV (exp on trans pipe overlaps next QK)
        float e0 = hwexp2(s0.x), e1 = hwexp2(s0.y), e2 = hwexp2(s0.z), e3 = hwexp2(s0.w);
        float e4 = hwexp2(s1.x), e5 = hwexp2(s1.y), e6 = hwexp2(s1.z), e7 = hwexp2(s1.w);
        ssum += ((e0 + e1) + (e2 + e3)) + ((e4 + e5) + (e6 + e7));
        U4 bp;
        bp.u.x = pk2bf_t(e0, e1); bp.u.y = pk2bf_t(e2, e3);
        bp.u.z = pk2bf_t(e4, e5); bp.u.w = pk2bf_t(e6, e7);
        if (gi & 1) {
            accB0 = __builtin_amdgcn_mfma_f32_16x16x32_bf16(v0.s, bp.s, accB0, 0, 0, 0);
            accB1 = __builtin_amdgcn_mfma_f32_16x16x32_bf16(v1.s, bp.s, accB1, 0, 0, 0);
        } else {
            accA0 = __builtin_amdgcn_mfma_f32_16x16x32_bf16(v0.s, bp.s, accA0, 0, 0, 0);
            accA1 = __builtin_amdgcn_mfma_f32_16x16x32_bf16(v1.s, bp.s, accA1, 0, 0, 0);
        }

        if (gi < 7) { v0 = v0n; v1 = v1n; s0 = s0n; s1 = s1n; }
    }

    f32x4 acc0 = accA0 + accB0;
    f32x4 acc1 = accA1 + accB1;

#pragma unroll
    for (int e = 0; e < 4; ++e) {
        sAcc[qh][kq][e][l]     = acc0[e];
        sAcc[qh][kq][4 + e][l] = acc1[e];
    }
    sSum[qh][kq][l] = ssum;
    __syncthreads();

    int qt_f = w & 1;
    int ot   = w >> 1;
    f32x4 ca0 = zz, ca1 = zz;
    float cs = 0.f;
#pragma unroll
    for (int k2 = 0; k2 < 4; ++k2) {
#pragma unroll
        for (int e = 0; e < 4; ++e) {
            ca0[e] += sAcc[qt_f][k2][e][l];
            ca1[e] += sAcc[qt_f][k2][4 + e][l];
        }
        cs += sSum[qt_f][k2][l];
    }
    cs += __shfl_xor(cs, 16, 64);
    cs += __shfl_xor(cs, 32, 64);
    float inv = 1.0f / cs;

    U4 mb;
    mb.u.x = pk2bf_t(ca0.x * inv, ca0.y * inv);
    mb.u.y = pk2bf_t(ca0.z * inv, ca0.w * inv);
    mb.u.z = pk2bf_t(ca1.x * inv, ca1.y * inv);
    mb.u.w = pk2bf_t(ca1.z * inv, ca1.w * inv);

    float gm = gamma[0];
    int q = qb + qt_f * 16 + q16;
    const float* xq = x + (size_t)b * CC * HW + q;
    float*       oq = out + (size_t)b * CC * HW + q;
    U4 wva;
    wva.u = *(const uint4*)(wvB + (size_t)(ot * 64 + l) * CK);
    f32x4 d = __builtin_amdgcn_mfma_f32_16x16x32_bf16(wva.s, mb.s, zz, 0, 0, 0);
#pragma unroll
    for (int r = 0; r < 4; ++r) {
        int o = ot * 16 + h * 4 + r;
        oq[(size_t)o * HW] = xq[(size_t)o * HW] + gm * (d[r] + bv[o]);
    }
}

extern "C" void kernel_launch(void* const* d_in, const int* in_sizes, int n_in,
                              void* d_out, int out_size, void* d_ws, size_t ws_size,
                              hipStream_t stream) {
    const float* x     = (const float*)d_in[0];
    const float* wf    = (const float*)d_in[1];
    const float* bf    = (const float*)d_in[2];
    const float* wg    = (const float*)d_in[3];
    const float* bg    = (const float*)d_in[4];
    const float* wh    = (const float*)d_in[5];
    const float* bh    = (const float*)d_in[6];
    const float* wv    = (const float*)d_in[7];
    const float* bv    = (const float*)d_in[8];
    const float* gamma = (const float*)d_in[9];
    float* out = (float*)d_out;
    char* ws = (char*)d_ws;

    unsigned short* fxB  = (unsigned short*)(ws + FXB_OFF);
    unsigned short* gxA  = (unsigned short*)(ws + GXA_OFF);
    unsigned short* hxC  = (unsigned short*)(ws + HXC_OFF);
    unsigned short* wvB  = (unsigned short*)(ws + WVB_OFF);
    unsigned short* frag = (unsigned short*)(ws + FRG_OFF);

    prep_kernel<<<dim3(256, 6), 256, 0, stream>>>(x, wf, bf, wg, bg, wh, bh, wv,
                                                  fxB, gxA, hxC, wvB);
    tile_kernel<<<512, 256, 0, stream>>>(gxA, hxC, frag);
    attn_kernel<<<2048, 512, 0, stream>>>(x, fxB, frag, wvB, bv, gamma, out);
}

// Round 22
// 42.842 us; speedup vs baseline: 1.2236x; 1.0964x over previous
//
#include <hip/hip_runtime.h>
#include <hip/hip_bf16.h>
#include <math.h>

#define BB 16
#define CC 64
#define HW 4096
#define MM 1024
#define CK 8
#define CV 32
#define LOG2E 1.4426950408889634f

typedef float f32x4 __attribute__((ext_vector_type(4)));
typedef short s16x8 __attribute__((ext_vector_type(8)));

union U4 { uint4 u; s16x8 s; };

__device__ inline unsigned short bfu(float a) {           // RNE (prep only)
    __hip_bfloat16 h = __float2bfloat16(a);
    union { __hip_bfloat16 h; unsigned short u; } c; c.h = h; return c.u;
}
__device__ inline unsigned int pk2bf(float a, float b) {  // RNE pack
    return (unsigned int)bfu(a) | ((unsigned int)bfu(b) << 16);
}
__device__ inline unsigned int pk2bf_t(float a, float b) { // trunc pack (attn)
    return (__float_as_uint(a) >> 16) | (__float_as_uint(b) & 0xffff0000u);
}

// Hardware exp2 (v_exp_f32, trans pipe). DIRECT A/B: hwexp2 46.25us total
// (R18) vs fexp2i 52.4us (R20) vs OCML ~52+ (R14) -- trans pipe overlaps
// VALU pack/ssum work.
__device__ inline float hwexp2(float s) {
#if __has_builtin(__builtin_amdgcn_exp2f)
    return __builtin_amdgcn_exp2f(s);
#else
    float r;
    asm volatile("v_exp_f32 %0, %1\n\ts_nop 1" : "=v"(r) : "v"(s));
    return r;
#endif
}

// Workspace layout (bytes):
//   fxB  bf16 [b][q][8]            @ 0        (1,048,576)
//   gxA  bf16 [b][k][8]            @ 1048576  (262,144)
//   hxC  bf16 [b][ch][k]           @ 1310720  (1,048,576)
//   wvB  bf16 tiled [4][64][8]     @ 2359296  (4,096)
//   frag bf16 [b][g][4][64][8]     @ 2363392  (2,097,152)
#define FXB_OFF 0
#define GXA_OFF 1048576
#define HXC_OFF 1310720
#define WVB_OFF 2359296
#define FRG_OFF 2363392

// ---------------------------------------------------------------------------
// Kernel A: conv f/g/h split by OUTPUT channels (blockIdx.y = chunk:
// 0=f, 1=g, 2..5=h quarters). Pool via shfl_xor(1,2). hxC staged via LDS.
// ---------------------------------------------------------------------------
__global__ __launch_bounds__(256, 6) void prep_kernel(
    const float* __restrict__ x,
    const float* __restrict__ wf, const float* __restrict__ bf,
    const float* __restrict__ wg, const float* __restrict__ bg,
    const float* __restrict__ wh, const float* __restrict__ bh,
    const float* __restrict__ wv,
    unsigned short* __restrict__ fxB, unsigned short* __restrict__ gxA,
    unsigned short* __restrict__ hxC, unsigned short* __restrict__ wvB)
{
    __shared__ __align__(16) float wsm[8 * CC];
    __shared__ __align__(16) unsigned short sHp[64][8];

    int tid   = threadIdx.x;
    int chunk = blockIdx.y;            // 0=f 1=g 2..5=h
    const float* wsrc = (chunk == 0) ? wf : (chunk == 1) ? wg : (wh + (size_t)(chunk - 2) * 8 * CC);
    const float* bsrc = (chunk == 0) ? bf : (chunk == 1) ? bg : (bh + (chunk - 2) * 8);

    for (int i = tid; i < 8 * CC; i += 256) wsm[i] = wsrc[i];

    if (blockIdx.x == 0 && chunk == 0) {
        int t = tid >> 6, ll = tid & 63;
        const float* wr = wv + (size_t)(t * 16 + (ll & 15)) * CV + ((ll >> 4) * 8);
        uint4 wu;
        wu.x = pk2bf(wr[0], wr[1]); wu.y = pk2bf(wr[2], wr[3]);
        wu.z = pk2bf(wr[4], wr[5]); wu.w = pk2bf(wr[6], wr[7]);
        *(uint4*)(wvB + (size_t)tid * 8) = wu;
    }
    __syncthreads();

    int wave = tid >> 6, l = tid & 63;
    int wp = blockIdx.x * 4 + wave;
    int b  = wp >> 6;
    int t2 = wp & 63;
    int rpair = t2 >> 1, chalf = t2 & 1;
    int col = chalf * 32 + (l >> 2) * 2 + (l & 1);
    int row = rpair * 2 + ((l >> 1) & 1);
    int pix = row * 64 + col;

    float o8[8];
#pragma unroll
    for (int o = 0; o < 8; ++o) o8[o] = bsrc[o];

    const float* xp = x + (size_t)b * CC * HW + pix;
#pragma unroll 4
    for (int c4 = 0; c4 < CC; c4 += 4) {
        float v0 = xp[(c4 + 0) * HW];
        float v1 = xp[(c4 + 1) * HW];
        float v2 = xp[(c4 + 2) * HW];
        float v3 = xp[(c4 + 3) * HW];
#pragma unroll
        for (int o = 0; o < 8; ++o) {
            float4 w = *(const float4*)&wsm[o * CC + c4];
            o8[o] = fmaf(w.x, v0, fmaf(w.y, v1, fmaf(w.z, v2, fmaf(w.w, v3, o8[o]))));
        }
    }

    if (chunk == 0) {
        uint4 fu;
        fu.x = pk2bf(o8[0] * LOG2E, o8[1] * LOG2E);
        fu.y = pk2bf(o8[2] * LOG2E, o8[3] * LOG2E);
        fu.z = pk2bf(o8[4] * LOG2E, o8[5] * LOG2E);
        fu.w = pk2bf(o8[6] * LOG2E, o8[7] * LOG2E);
        *(uint4*)(fxB + (size_t)(b * HW + pix) * CK) = fu;
    } else {
#pragma unroll
        for (int o = 0; o < 8; ++o) {
            o8[o] = fmaxf(o8[o], __shfl_xor(o8[o], 1, 64));
            o8[o] = fmaxf(o8[o], __shfl_xor(o8[o], 2, 64));
        }
        int ppl = l >> 2;
        if (chunk == 1) {
            if ((l & 3) == 0) {
                uint4 gu;
                gu.x = pk2bf(o8[0], o8[1]); gu.y = pk2bf(o8[2], o8[3]);
                gu.z = pk2bf(o8[4], o8[5]); gu.w = pk2bf(o8[6], o8[7]);
                *(uint4*)(gxA + (size_t)(b * MM + t2 * 16 + ppl) * CK) = gu;
            }
        } else {
            if ((l & 3) == 0) {
                uint4 hu;
                hu.x = pk2bf(o8[0], o8[1]); hu.y = pk2bf(o8[2], o8[3]);
                hu.z = pk2bf(o8[4], o8[5]); hu.w = pk2bf(o8[6], o8[7]);
                *(uint4*)&sHp[wave * 16 + ppl][0] = hu;
            }
            __syncthreads();
            int ch = tid >> 5, j = tid & 31;
            unsigned int v = (unsigned int)sHp[2 * j][ch]
                           | ((unsigned int)sHp[2 * j + 1][ch] << 16);
            int ppb = (blockIdx.x * 4 & 63) * 16;
            int chg = (chunk - 2) * 8 + ch;
            *(unsigned int*)(hxC + (size_t)(b * CV + chg) * MM + ppb + 2 * j) = v;
        }
    }
}

// ---------------------------------------------------------------------------
// Kernel T: wave-exact operand tiles frag[b][g][4][64][8] (see R10).
// ---------------------------------------------------------------------------
__global__ __launch_bounds__(256) void tile_kernel(
    const unsigned short* __restrict__ gxA, const unsigned short* __restrict__ hxC,
    unsigned short* __restrict__ frag)
{
    int bg = blockIdx.x;
    int b  = bg >> 5, g = bg & 31;
    int tid = threadIdx.x;
    int which = tid >> 6, l = tid & 63;
    int q16 = l & 15, h = l >> 4;
    int prm = ((q16 & 12) << 1) | (q16 & 3);

    const unsigned short* src;
    if (which < 2) {
        src = gxA + (size_t)(b * MM + g * 32 + prm + (which ? 4 : 0)) * CK;
    } else {
        src = hxC + (size_t)(b * CV + prm + ((which == 3) ? 4 : 0)) * MM + g * 32 + h * 8;
    }
    uint4 v = *(const uint4*)src;
    *(uint4*)(frag + ((size_t)bg * 4 + which) * 64 * 8 + (size_t)l * 8) = v;
}

// ---------------------------------------------------------------------------
// Kernel B: MFMA flash attention. Block = 64 queries, 512 thr (8 waves).
// Wave w: qt-PAIR qg=w>>2 (Q-tiles 2qg,2qg+1), key-quarter kq=w&3.
// R22 = R8's 2-Q-tile structure, done right: frag loads + hwexp2 +
// (512,4)=128-VGPR cap (R8 died on the (512,8) 64-cap spill, not the
// structure). 2 Q-tiles share each 4KB frag group -> frag traffic HALVES
// (512->256MB L2) and MFMA:load doubles to 8:4; two independent exp/pack
// chains per group. ~85 VGPR, no spill expected. LDS 36KB -> 4 blocks/CU.
// Epilogue: wave w combines qt_f=w&3, writes ot-half oth=w>>2.
// ---------------------------------------------------------------------------
__global__ __launch_bounds__(512, 4) void attn_kernel(
    const float* __restrict__ x,
    const unsigned short* __restrict__ fxB, const unsigned short* __restrict__ frag,
    const unsigned short* __restrict__ wvB,
    const float* __restrict__ bv, const float* __restrict__ gamma,
    float* __restrict__ out)
{
    __shared__ float sAcc[4][4][8][64];   // [qt][kq][elem][lane] 32KB
    __shared__ float sSum[4][4][64];      // 4KB

    int tid = threadIdx.x;
    int l   = tid & 63;
    int w   = tid >> 6;                        // 0..7
    int qg  = w >> 2;                          // qt pair
    int kq  = w & 3;                           // key quarter
    int b   = blockIdx.x >> 6;                 // 64 blocks per batch
    int qb  = (blockIdx.x & 63) * 64;
    int q16 = l & 15;
    int h   = l >> 4;
    bool lo16 = (l < 16);

    // Q fragments for the wave's two Q-tiles
    U4 qf0, qf1;
    {
        uint4 v = *(const uint4*)(fxB + (size_t)(b * HW + qb + (qg * 2 + 0) * 16 + q16) * CK);
        if (!lo16) { v.x = 0; v.y = 0; v.z = 0; v.w = 0; }
        qf0.u = v;
        uint4 v2 = *(const uint4*)(fxB + (size_t)(b * HW + qb + (qg * 2 + 1) * 16 + q16) * CK);
        if (!lo16) { v2.x = 0; v2.y = 0; v2.z = 0; v2.w = 0; }
        qf1.u = v2;
    }

    f32x4 zz = {0.f, 0.f, 0.f, 0.f};
    f32x4 a00 = zz, a01 = zz, a10 = zz, a11 = zz;  // [tile][v-half]
    float ssum0 = 0.f, ssum1 = 0.f;

    const unsigned short* fb = frag + ((size_t)(b * 32 + kq * 8) * 4) * 64 * 8
                                    + (size_t)l * 8;

#pragma unroll 2
    for (int gi = 0; gi < 8; ++gi) {
        U4 ga, gb2, v0, v1;
        ga.u  = *(const uint4*)(fb + 0 * 512);
        gb2.u = *(const uint4*)(fb + 1 * 512);
        v0.u  = *(const uint4*)(fb + 2 * 512);
        v1.u  = *(const uint4*)(fb + 3 * 512);
        fb += 2048;

        // tile 0
        f32x4 s0 = __builtin_amdgcn_mfma_f32_16x16x32_bf16(ga.s,  qf0.s, zz, 0, 0, 0);
        f32x4 s1 = __builtin_amdgcn_mfma_f32_16x16x32_bf16(gb2.s, qf0.s, zz, 0, 0, 0);
        // tile 1 (independent chain)
        f32x4 t0 = __builtin_amdgcn_mfma_f32_16x16x32_bf16(ga.s,  qf1.s, zz, 0, 0, 0);
        f32x4 t1 = __builtin_amdgcn_mfma_f32_16x16x32_bf16(gb2.s, qf1.s, zz, 0, 0, 0);

        float e0 = hwexp2(s0.x), e1 = hwexp2(s0.y), e2 = hwexp2(s0.z), e3 = hwexp2(s0.w);
        float e4 = hwexp2(s1.x), e5 = hwexp2(s1.y), e6 = hwexp2(s1.z), e7 = hwexp2(s1.w);
        float f0 = hwexp2(t0.x), f1 = hwexp2(t0.y), f2 = hwexp2(t0.z), f3 = hwexp2(t0.w);
        float f4 = hwexp2(t1.x), f5 = hwexp2(t1.y), f6 = hwexp2(t1.z), f7 = hwexp2(t1.w);
        ssum0 += ((e0 + e1) + (e2 + e3)) + ((e4 + e5) + (e6 + e7));
        ssum1 += ((f0 + f1) + (f2 + f3)) + ((f4 + f5) + (f6 + f7));

        U4 bp0, bp1;
        bp0.u.x = pk2bf_t(e0, e1); bp0.u.y = pk2bf_t(e2, e3);
        bp0.u.z = pk2bf_t(e4, e5); bp0.u.w = pk2bf_t(e6, e7);
        bp1.u.x = pk2bf_t(f0, f1); bp1.u.y = pk2bf_t(f2, f3);
        bp1.u.z = pk2bf_t(f4, f5); bp1.u.w = pk2bf_t(f6, f7);

        a00 = __builtin_amdgcn_mfma_f32_16x16x32_bf16(v0.s, bp0.s, a00, 0, 0, 0);
        a01 = __builtin_amdgcn_mfma_f32_16x16x32_bf16(v1.s, bp0.s, a01, 0, 0, 0);
        a10 = __builtin_amdgcn_mfma_f32_16x16x32_bf16(v0.s, bp1.s, a10, 0, 0, 0);
        a11 = __builtin_amdgcn_mfma_f32_16x16x32_bf16(v1.s, bp1.s, a11, 0, 0, 0);
    }

    // publish partials (element-major: lane-stride-1, conflict-free)
    {
        int qt0 = qg * 2, qt1 = qg * 2 + 1;
#pragma unroll
        for (int e = 0; e < 4; ++e) {
            sAcc[qt0][kq][e][l]     = a00[e];
            sAcc[qt0][kq][4 + e][l] = a01[e];
            sAcc[qt1][kq][e][l]     = a10[e];
            sAcc[qt1][kq][4 + e][l] = a11[e];
        }
        sSum[qt0][kq][l] = ssum0;
        sSum[qt1][kq][l] = ssum1;
    }
    __syncthreads();

    // wave w combines qt_f = w&3, writes ot-half oth = w>>2
    int qt_f = w & 3;
    int oth  = w >> 2;
    f32x4 ca0 = zz, ca1 = zz;
    float cs = 0.f;
#pragma unroll
    for (int k2 = 0; k2 < 4; ++k2) {
#pragma unroll
        for (int e = 0; e < 4; ++e) {
            ca0[e] += sAcc[qt_f][k2][e][l];
            ca1[e] += sAcc[qt_f][k2][4 + e][l];
        }
        cs += sSum[qt_f][k2][l];
    }
    cs += __shfl_xor(cs, 16, 64);
    cs += __shfl_xor(cs, 32, 64);
    float inv = 1.0f / cs;

    U4 mb;
    mb.u.x = pk2bf_t(ca0.x * inv, ca0.y * inv);
    mb.u.y = pk2bf_t(ca0.z * inv, ca0.w * inv);
    mb.u.z = pk2bf_t(ca1.x * inv, ca1.y * inv);
    mb.u.w = pk2bf_t(ca1.z * inv, ca1.w * inv);

    float gm = gamma[0];
    int q = qb + qt_f * 16 + q16;
    const float* xq = x + (size_t)b * CC * HW + q;
    float*       oq = out + (size_t)b * CC * HW + q;
#pragma unroll
    for (int i = 0; i < 2; ++i) {
        int ot = oth * 2 + i;
        U4 wva;
        wva.u = *(const uint4*)(wvB + (size_t)(ot * 64 + l) * CK);
        f32x4 d = __builtin_amdgcn_mfma_f32_16x16x32_bf16(wva.s, mb.s, zz, 0, 0, 0);
#pragma unroll
        for (int r = 0; r < 4; ++r) {
            int o = ot * 16 + h * 4 + r;
            oq[(size_t)o * HW] = xq[(size_t)o * HW] + gm * (d[r] + bv[o]);
        }
    }
}

extern "C" void kernel_launch(void* const* d_in, const int* in_sizes, int n_in,
                              void* d_out, int out_size, void* d_ws, size_t ws_size,
                              hipStream_t stream) {
    const float* x     = (const float*)d_in[0];
    const float* wf    = (const float*)d_in[1];
    const float* bf    = (const float*)d_in[2];
    const float* wg    = (const float*)d_in[3];
    const float* bg    = (const float*)d_in[4];
    const float* wh    = (const float*)d_in[5];
    const float* bh    = (const float*)d_in[6];
    const float* wv    = (const float*)d_in[7];
    const float* bv    = (const float*)d_in[8];
    const float* gamma = (const float*)d_in[9];
    float* out = (float*)d_out;
    char* ws = (char*)d_ws;

    unsigned short* fxB  = (unsigned short*)(ws + FXB_OFF);
    unsigned short* gxA  = (unsigned short*)(ws + GXA_OFF);
    unsigned short* hxC  = (unsigned short*)(ws + HXC_OFF);
    unsigned short* wvB  = (unsigned short*)(ws + WVB_OFF);
    unsigned short* frag = (unsigned short*)(ws + FRG_OFF);

    prep_kernel<<<dim3(256, 6), 256, 0, stream>>>(x, wf, bf, wg, bg, wh, bh, wv,
                                                  fxB, gxA, hxC, wvB);
    tile_kernel<<<512, 256, 0, stream>>>(gxA, hxC, frag);
    // Kernel B: 1024 blocks x 512 thr; 64 q/block, (qt-pair x key-quarter)
    attn_kernel<<<1024, 512, 0, stream>>>(x, fxB, frag, wvB, bv, gamma, out);
}

// Round 23
// 42.713 us; speedup vs baseline: 1.2273x; 1.0030x over previous
//
#include <hip/hip_runtime.h>
#include <hip/hip_bf16.h>
#include <math.h>

#define BB 16
#define CC 64
#define HW 4096
#define MM 1024
#define CK 8
#define CV 32
#define LOG2E 1.4426950408889634f

typedef float f32x4 __attribute__((ext_vector_type(4)));
typedef short s16x8 __attribute__((ext_vector_type(8)));

union U4 { uint4 u; s16x8 s; };

__device__ inline unsigned short bfu(float a) {           // RNE (prep only)
    __hip_bfloat16 h = __float2bfloat16(a);
    union { __hip_bfloat16 h; unsigned short u; } c; c.h = h; return c.u;
}
__device__ inline unsigned int pk2bf(float a, float b) {  // RNE pack
    return (unsigned int)bfu(a) | ((unsigned int)bfu(b) << 16);
}
__device__ inline unsigned int pk2bf_t(float a, float b) { // trunc pack (attn)
    return (__float_as_uint(a) >> 16) | (__float_as_uint(b) & 0xffff0000u);
}

// Hardware exp2 (v_exp_f32, trans pipe). DIRECT A/B: hwexp2 46.25us total
// (R18) vs fexp2i 52.4us (R20) -- trans pipe overlaps VALU pack/ssum work.
__device__ inline float hwexp2(float s) {
#if __has_builtin(__builtin_amdgcn_exp2f)
    return __builtin_amdgcn_exp2f(s);
#else
    float r;
    asm volatile("v_exp_f32 %0, %1\n\ts_nop 1" : "=v"(r) : "v"(s));
    return r;
#endif
}

// Workspace layout (bytes):
//   fxB  bf16 [b][q][8]            @ 0        (1,048,576)
//   gxA  bf16 [b][k][8]            @ 1048576  (262,144)
//   hxC  bf16 [b][ch][k]           @ 1310720  (1,048,576)
//   wvB  bf16 tiled [4][64][8]     @ 2359296  (4,096)
//   frag bf16 [b][g][4][64][8]     @ 2363392  (2,097,152)
#define FXB_OFF 0
#define GXA_OFF 1048576
#define HXC_OFF 1310720
#define WVB_OFF 2359296
#define FRG_OFF 2363392

// ---------------------------------------------------------------------------
// Kernel A: conv f/g/h split by OUTPUT channels (blockIdx.y = chunk:
// 0=f, 1=g, 2..5=h quarters). Pool via shfl_xor(1,2). hxC staged via LDS.
// ---------------------------------------------------------------------------
__global__ __launch_bounds__(256, 6) void prep_kernel(
    const float* __restrict__ x,
    const float* __restrict__ wf, const float* __restrict__ bf,
    const float* __restrict__ wg, const float* __restrict__ bg,
    const float* __restrict__ wh, const float* __restrict__ bh,
    const float* __restrict__ wv,
    unsigned short* __restrict__ fxB, unsigned short* __restrict__ gxA,
    unsigned short* __restrict__ hxC, unsigned short* __restrict__ wvB)
{
    __shared__ __align__(16) float wsm[8 * CC];
    __shared__ __align__(16) unsigned short sHp[64][8];

    int tid   = threadIdx.x;
    int chunk = blockIdx.y;            // 0=f 1=g 2..5=h
    const float* wsrc = (chunk == 0) ? wf : (chunk == 1) ? wg : (wh + (size_t)(chunk - 2) * 8 * CC);
    const float* bsrc = (chunk == 0) ? bf : (chunk == 1) ? bg : (bh + (chunk - 2) * 8);

    for (int i = tid; i < 8 * CC; i += 256) wsm[i] = wsrc[i];

    if (blockIdx.x == 0 && chunk == 0) {
        int t = tid >> 6, ll = tid & 63;
        const float* wr = wv + (size_t)(t * 16 + (ll & 15)) * CV + ((ll >> 4) * 8);
        uint4 wu;
        wu.x = pk2bf(wr[0], wr[1]); wu.y = pk2bf(wr[2], wr[3]);
        wu.z = pk2bf(wr[4], wr[5]); wu.w = pk2bf(wr[6], wr[7]);
        *(uint4*)(wvB + (size_t)tid * 8) = wu;
    }
    __syncthreads();

    int wave = tid >> 6, l = tid & 63;
    int wp = blockIdx.x * 4 + wave;
    int b  = wp >> 6;
    int t2 = wp & 63;
    int rpair = t2 >> 1, chalf = t2 & 1;
    int col = chalf * 32 + (l >> 2) * 2 + (l & 1);
    int row = rpair * 2 + ((l >> 1) & 1);
    int pix = row * 64 + col;

    float o8[8];
#pragma unroll
    for (int o = 0; o < 8; ++o) o8[o] = bsrc[o];

    const float* xp = x + (size_t)b * CC * HW + pix;
#pragma unroll 4
    for (int c4 = 0; c4 < CC; c4 += 4) {
        float v0 = xp[(c4 + 0) * HW];
        float v1 = xp[(c4 + 1) * HW];
        float v2 = xp[(c4 + 2) * HW];
        float v3 = xp[(c4 + 3) * HW];
#pragma unroll
        for (int o = 0; o < 8; ++o) {
            float4 w = *(const float4*)&wsm[o * CC + c4];
            o8[o] = fmaf(w.x, v0, fmaf(w.y, v1, fmaf(w.z, v2, fmaf(w.w, v3, o8[o]))));
        }
    }

    if (chunk == 0) {
        uint4 fu;
        fu.x = pk2bf(o8[0] * LOG2E, o8[1] * LOG2E);
        fu.y = pk2bf(o8[2] * LOG2E, o8[3] * LOG2E);
        fu.z = pk2bf(o8[4] * LOG2E, o8[5] * LOG2E);
        fu.w = pk2bf(o8[6] * LOG2E, o8[7] * LOG2E);
        *(uint4*)(fxB + (size_t)(b * HW + pix) * CK) = fu;
    } else {
#pragma unroll
        for (int o = 0; o < 8; ++o) {
            o8[o] = fmaxf(o8[o], __shfl_xor(o8[o], 1, 64));
            o8[o] = fmaxf(o8[o], __shfl_xor(o8[o], 2, 64));
        }
        int ppl = l >> 2;
        if (chunk == 1) {
            if ((l & 3) == 0) {
                uint4 gu;
                gu.x = pk2bf(o8[0], o8[1]); gu.y = pk2bf(o8[2], o8[3]);
                gu.z = pk2bf(o8[4], o8[5]); gu.w = pk2bf(o8[6], o8[7]);
                *(uint4*)(gxA + (size_t)(b * MM + t2 * 16 + ppl) * CK) = gu;
            }
        } else {
            if ((l & 3) == 0) {
                uint4 hu;
                hu.x = pk2bf(o8[0], o8[1]); hu.y = pk2bf(o8[2], o8[3]);
                hu.z = pk2bf(o8[4], o8[5]); hu.w = pk2bf(o8[6], o8[7]);
                *(uint4*)&sHp[wave * 16 + ppl][0] = hu;
            }
            __syncthreads();
            int ch = tid >> 5, j = tid & 31;
            unsigned int v = (unsigned int)sHp[2 * j][ch]
                           | ((unsigned int)sHp[2 * j + 1][ch] << 16);
            int ppb = (blockIdx.x * 4 & 63) * 16;
            int chg = (chunk - 2) * 8 + ch;
            *(unsigned int*)(hxC + (size_t)(b * CV + chg) * MM + ppb + 2 * j) = v;
        }
    }
}

// ---------------------------------------------------------------------------
// Kernel T: wave-exact operand tiles frag[b][g][4][64][8] (see R10).
// ---------------------------------------------------------------------------
__global__ __launch_bounds__(256) void tile_kernel(
    const unsigned short* __restrict__ gxA, const unsigned short* __restrict__ hxC,
    unsigned short* __restrict__ frag)
{
    int bg = blockIdx.x;
    int b  = bg >> 5, g = bg & 31;
    int tid = threadIdx.x;
    int which = tid >> 6, l = tid & 63;
    int q16 = l & 15, h = l >> 4;
    int prm = ((q16 & 12) << 1) | (q16 & 3);

    const unsigned short* src;
    if (which < 2) {
        src = gxA + (size_t)(b * MM + g * 32 + prm + (which ? 4 : 0)) * CK;
    } else {
        src = hxC + (size_t)(b * CV + prm + ((which == 3) ? 4 : 0)) * MM + g * 32 + h * 8;
    }
    uint4 v = *(const uint4*)src;
    *(uint4*)(frag + ((size_t)bg * 4 + which) * 64 * 8 + (size_t)l * 8) = v;
}

// ---------------------------------------------------------------------------
// Kernel B: MFMA flash attention. Block = 64 queries, 512 thr (8 waves).
// R23 = T=4: EVERY wave computes ALL 4 Q-tiles over its key-EIGHTH
// (kq = w, 128 keys = 4 frag groups). T-scaling is the only lever that has
// moved attn (R18 T=1: 46.25 total; R22 T=2: 42.84): 4 loads now amortize
// over 8 QK + 32 exp + 8 PV with 4 INDEPENDENT tile-chains, and frag
// traffic halves again (256->128MB). LDS combine 72KB -> 2 blocks/CU =
// 16 waves/CU -- but ~110 VGPR caps residency at 16 waves/CU anyway, so
// nothing lost. Combine: 2 waves per qt (qt_f=w>>1), 2 ot each (oth=w&1).
// (512,4) = 128-VGPR cap (proven safe bound).
// ---------------------------------------------------------------------------
__global__ __launch_bounds__(512, 4) void attn_kernel(
    const float* __restrict__ x,
    const unsigned short* __restrict__ fxB, const unsigned short* __restrict__ frag,
    const unsigned short* __restrict__ wvB,
    const float* __restrict__ bv, const float* __restrict__ gamma,
    float* __restrict__ out)
{
    __shared__ float sAcc[4][8][8][64];   // [qt][kq][elem][lane] 64KB
    __shared__ float sSum[4][8][64];      // 8KB

    int tid = threadIdx.x;
    int l   = tid & 63;
    int w   = tid >> 6;                        // 0..7 = key eighth
    int b   = blockIdx.x >> 6;                 // 64 blocks per batch
    int qb  = (blockIdx.x & 63) * 64;
    int q16 = l & 15;
    int h   = l >> 4;
    bool lo16 = (l < 16);

    // Q fragments for all 4 Q-tiles
    U4 qf[4];
#pragma unroll
    for (int t = 0; t < 4; ++t) {
        uint4 v = *(const uint4*)(fxB + (size_t)(b * HW + qb + t * 16 + q16) * CK);
        if (!lo16) { v.x = 0; v.y = 0; v.z = 0; v.w = 0; }
        qf[t].u = v;
    }

    f32x4 zz = {0.f, 0.f, 0.f, 0.f};
    f32x4 acc[4][2];
#pragma unroll
    for (int t = 0; t < 4; ++t) { acc[t][0] = zz; acc[t][1] = zz; }
    float ssum[4] = {0.f, 0.f, 0.f, 0.f};

    const unsigned short* fb = frag + ((size_t)(b * 32 + w * 4) * 4) * 64 * 8
                                    + (size_t)l * 8;

#pragma unroll 2
    for (int gi = 0; gi < 4; ++gi) {
        U4 ga, gb2, v0, v1;
        ga.u  = *(const uint4*)(fb + 0 * 512);
        gb2.u = *(const uint4*)(fb + 1 * 512);
        v0.u  = *(const uint4*)(fb + 2 * 512);
        v1.u  = *(const uint4*)(fb + 3 * 512);
        fb += 2048;

#pragma unroll
        for (int t = 0; t < 4; ++t) {
            f32x4 s0 = __builtin_amdgcn_mfma_f32_16x16x32_bf16(ga.s,  qf[t].s, zz, 0, 0, 0);
            f32x4 s1 = __builtin_amdgcn_mfma_f32_16x16x32_bf16(gb2.s, qf[t].s, zz, 0, 0, 0);
            float e0 = hwexp2(s0.x), e1 = hwexp2(s0.y), e2 = hwexp2(s0.z), e3 = hwexp2(s0.w);
            float e4 = hwexp2(s1.x), e5 = hwexp2(s1.y), e6 = hwexp2(s1.z), e7 = hwexp2(s1.w);
            ssum[t] += ((e0 + e1) + (e2 + e3)) + ((e4 + e5) + (e6 + e7));
            U4 bp;
            bp.u.x = pk2bf_t(e0, e1); bp.u.y = pk2bf_t(e2, e3);
            bp.u.z = pk2bf_t(e4, e5); bp.u.w = pk2bf_t(e6, e7);
            acc[t][0] = __builtin_amdgcn_mfma_f32_16x16x32_bf16(v0.s, bp.s, acc[t][0], 0, 0, 0);
            acc[t][1] = __builtin_amdgcn_mfma_f32_16x16x32_bf16(v1.s, bp.s, acc[t][1], 0, 0, 0);
        }
    }

    // publish partials (element-major: lane-stride-1, conflict-free)
#pragma unroll
    for (int t = 0; t < 4; ++t) {
#pragma unroll
        for (int e = 0; e < 4; ++e) {
            sAcc[t][w][e][l]     = acc[t][0][e];
            sAcc[t][w][4 + e][l] = acc[t][1][e];
        }
        sSum[t][w][l] = ssum[t];
    }
    __syncthreads();

    // wave w combines qt_f = w>>1, writes ot pair oth = w&1
    int qt_f = w >> 1;
    int oth  = w & 1;
    f32x4 ca0 = zz, ca1 = zz;
    float cs = 0.f;
#pragma unroll
    for (int k2 = 0; k2 < 8; ++k2) {
#pragma unroll
        for (int e = 0; e < 4; ++e) {
            ca0[e] += sAcc[qt_f][k2][e][l];
            ca1[e] += sAcc[qt_f][k2][4 + e][l];
        }
        cs += sSum[qt_f][k2][l];
    }
    cs += __shfl_xor(cs, 16, 64);
    cs += __shfl_xor(cs, 32, 64);
    float inv = 1.0f / cs;

    U4 mb;
    mb.u.x = pk2bf_t(ca0.x * inv, ca0.y * inv);
    mb.u.y = pk2bf_t(ca0.z * inv, ca0.w * inv);
    mb.u.z = pk2bf_t(ca1.x * inv, ca1.y * inv);
    mb.u.w = pk2bf_t(ca1.z * inv, ca1.w * inv);

    float gm = gamma[0];
    int q = qb + qt_f * 16 + q16;
    const float* xq = x + (size_t)b * CC * HW + q;
    float*       oq = out + (size_t)b * CC * HW + q;
#pragma unroll
    for (int i = 0; i < 2; ++i) {
        int ot = oth * 2 + i;
        U4 wva;
        wva.u = *(const uint4*)(wvB + (size_t)(ot * 64 + l) * CK);
        f32x4 d = __builtin_amdgcn_mfma_f32_16x16x32_bf16(wva.s, mb.s, zz, 0, 0, 0);
#pragma unroll
        for (int r = 0; r < 4; ++r) {
            int o = ot * 16 + h * 4 + r;
            oq[(size_t)o * HW] = xq[(size_t)o * HW] + gm * (d[r] + bv[o]);
        }
    }
}

extern "C" void kernel_launch(void* const* d_in, const int* in_sizes, int n_in,
                              void* d_out, int out_size, void* d_ws, size_t ws_size,
                              hipStream_t stream) {
    const float* x     = (const float*)d_in[0];
    const float* wf    = (const float*)d_in[1];
    const float* bf    = (const float*)d_in[2];
    const float* wg    = (const float*)d_in[3];
    const float* bg    = (const float*)d_in[4];
    const float* wh    = (const float*)d_in[5];
    const float* bh    = (const float*)d_in[6];
    const float* wv    = (const float*)d_in[7];
    const float* bv    = (const float*)d_in[8];
    const float* gamma = (const float*)d_in[9];
    float* out = (float*)d_out;
    char* ws = (char*)d_ws;

    unsigned short* fxB  = (unsigned short*)(ws + FXB_OFF);
    unsigned short* gxA  = (unsigned short*)(ws + GXA_OFF);
    unsigned short* hxC  = (unsigned short*)(ws + HXC_OFF);
    unsigned short* wvB  = (unsigned short*)(ws + WVB_OFF);
    unsigned short* frag = (unsigned short*)(ws + FRG_OFF);

    prep_kernel<<<dim3(256, 6), 256, 0, stream>>>(x, wf, bf, wg, bg, wh, bh, wv,
                                                  fxB, gxA, hxC, wvB);
    tile_kernel<<<512, 256, 0, stream>>>(gxA, hxC, frag);
    // Kernel B: 1024 blocks x 512 thr; 64 q/block, T=4 Q-tiles x key-eighths
    attn_kernel<<<1024, 512, 0, stream>>>(x, fxB, frag, wvB, bv, gamma, out);
}